// Round 9
// baseline (206.855 us; speedup 1.0000x reference)
//
#include <hip/hip_runtime.h>
#include <cstdint>

typedef unsigned short u16;
typedef unsigned int u32;
typedef __attribute__((ext_vector_type(8))) short bf16x8;   // 8 bf16 in 4 VGPRs
typedef __attribute__((ext_vector_type(4))) float f32x4;

#if __has_builtin(__builtin_amdgcn_exp2f)
#define EXP2(x) __builtin_amdgcn_exp2f(x)
#else
#define EXP2(x) exp2f(x)
#endif

__device__ __forceinline__ u16 f2bf(float f) {  // RNE
  unsigned u = __float_as_uint(f);
  u += 0x7fffu + ((u >> 16) & 1u);
  return (u16)(u >> 16);
}
__device__ __forceinline__ u32 pk_bf16(float lo, float hi) {  // RNE pack
#if __has_builtin(__builtin_amdgcn_cvt_pk_bf16_f32)
  auto r = __builtin_amdgcn_cvt_pk_bf16_f32(lo, hi);
  return __builtin_bit_cast(u32, r);
#else
  u32 a = __float_as_uint(lo), b = __float_as_uint(hi);
  a += 0x7fffu + ((a >> 16) & 1u);
  b += 0x7fffu + ((b >> 16) & 1u);
  return (a >> 16) | (b & 0xffff0000u);
#endif
}

// async global->LDS, 16B per lane. LDS dest must be wave-uniform base + lane*16.
__device__ __forceinline__ void async_load16(const void* g, void* l) {
  typedef const __attribute__((address_space(1))) void* gp_t;
  typedef __attribute__((address_space(3))) void* lp_t;
  __builtin_amdgcn_global_load_lds((gp_t)(uintptr_t)g, (lp_t)(uintptr_t)l, 16, 0, 0);
}

// ------- fused preprocess: x f32->bf16 copy (blocks [0,2048)) + both weight
//         transposes (blocks [2048,3072)) in ONE launch -------
__global__ __launch_bounds__(256) void preprocess(
    const float* __restrict__ x, u16* __restrict__ xb,
    const float* __restrict__ wqkv, u16* __restrict__ dqkv,
    const float* __restrict__ wout, u16* __restrict__ dout)
{
  __shared__ u16 tile[64][65];
  const int t = threadIdx.x;
  const int bx = blockIdx.x;
  if (bx < 2048) {
    const size_t i = ((size_t)bx * 256 + t) * 8;
    const float4 a = *(const float4*)(x + i);
    const float4 b = *(const float4*)(x + i + 4);
    union { u16 u[8]; bf16x8 v; } p;
    p.u[0] = f2bf(a.x); p.u[1] = f2bf(a.y); p.u[2] = f2bf(a.z); p.u[3] = f2bf(a.w);
    p.u[4] = f2bf(b.x); p.u[5] = f2bf(b.y); p.u[6] = f2bf(b.z); p.u[7] = f2bf(b.w);
    *(bf16x8*)(xb + i) = p.v;
    return;
  }
  const int tb = bx - 2048;            // 0..1023
  const int bxx = tb & 63, byy = tb >> 6;
  const bool isOut = bxx >= 48;
  const float* src = isOut ? wout : wqkv;
  u16* dst = isOut ? dout : dqkv;
  const int cols = isOut ? 1024 : 3072;
  const int rows = 1024;
  const int tc = (isOut ? (bxx - 48) : bxx) * 64;
  const int tr = byy * 64;
  const int r = t >> 2, c0 = (t & 3) * 16;
  const float* sp = src + (size_t)(tr + r) * cols + tc + c0;
#pragma unroll
  for (int i = 0; i < 16; i += 4) {
    const float4 v = *(const float4*)(sp + i);
    tile[r][c0 + i + 0] = f2bf(v.x);
    tile[r][c0 + i + 1] = f2bf(v.y);
    tile[r][c0 + i + 2] = f2bf(v.z);
    tile[r][c0 + i + 3] = f2bf(v.w);
  }
  __syncthreads();
  u16* dp = dst + (size_t)(tc + r) * rows + tr + c0;
#pragma unroll
  for (int i = 0; i < 16; ++i) dp[i] = tile[c0 + i][r];
}

// ------- batched V transpose: src [bh][2048][64] -> dst [bh][64][2048] (coalesced) ---
__global__ __launch_bounds__(256) void transpose_v(
    const u16* __restrict__ src, u16* __restrict__ dst)
{
  __shared__ u16 tile[64][72];
  const int t = threadIdx.x;
  const int r = t >> 2, c0 = (t & 3) * 16;
  const int bh = blockIdx.y, s0 = blockIdx.x * 64;
  const u16* sp = src + ((size_t)bh * 2048 + s0 + r) * 64 + c0;
  union { u16 u[8]; bf16x8 v; } a, b;
  a.v = *(const bf16x8*)sp;
  b.v = *(const bf16x8*)(sp + 8);
#pragma unroll
  for (int i = 0; i < 8; ++i) tile[r][c0 + i] = a.u[i];
#pragma unroll
  for (int i = 0; i < 8; ++i) tile[r][c0 + 8 + i] = b.u[i];
  __syncthreads();
  union { u16 u[8]; bf16x8 v; } x, y;
#pragma unroll
  for (int i = 0; i < 8; ++i) x.u[i] = tile[c0 + i][r];
#pragma unroll
  for (int i = 0; i < 8; ++i) y.u[i] = tile[c0 + 8 + i][r];
  u16* dp = dst + ((size_t)bh * 64 + r) * 2048 + s0 + c0;
  *(bf16x8*)dp = x.v;
  *(bf16x8*)(dp + 8) = y.v;
}

// ---------------- QKV GEMM with LDS-restaged coalesced epilogue -------------------
// C[m][n] = sum_k A[m][k]*Bt[n][k] + bias[n]; n = h*192+which*64+d.
// Epilogue: C-tile -> LDS (16B-group XOR swizzle) -> each thread stores one full
// 64-d row segment as 8 x b128 (was 64 scattered b16 stores).
__global__ __launch_bounds__(256) void gemm_qkv(
    const u16* __restrict__ A, const u16* __restrict__ Bt, const float* __restrict__ bias,
    u16* __restrict__ Qp, u16* __restrict__ Kp, u16* __restrict__ Vp, int Kd)
{
  __shared__ __align__(16) u16 As[128 * 32];
  __shared__ __align__(16) u16 Bs[128 * 32];
  __shared__ __align__(16) u16 Cs[128 * 128];
  const int t = threadIdx.x;
  const int lane = t & 63, wave = t >> 6;
  const int quad = lane >> 4, m16 = lane & 15;
  const int mb = blockIdx.y * 128, nb = blockIdx.x * 128;
  const int wr = (wave & 1) * 64, wc = (wave >> 1) * 64;

  const int srow = t >> 2;
  const int scol = (t & 3) * 8;
  const u16* Ag0 = A + (size_t)(mb + srow) * Kd + scol;
  const u16* Ag1 = Ag0 + (size_t)64 * Kd;
  const u16* Bg0 = Bt + (size_t)(nb + srow) * Kd + scol;
  const u16* Bg1 = Bg0 + (size_t)64 * Kd;
  u16* AsD = As + t * 8;
  u16* BsD = Bs + t * 8;

  f32x4 acc[4][4] = {};

  for (int k0 = 0; k0 < Kd; k0 += 32) {
    __syncthreads();
    async_load16(Ag0 + k0, AsD);
    async_load16(Ag1 + k0, AsD + 2048);
    async_load16(Bg0 + k0, BsD);
    async_load16(Bg1 + k0, BsD + 2048);
    __syncthreads();
    bf16x8 af[4], bfr[4];
#pragma unroll
    for (int i = 0; i < 4; ++i)
      af[i] = *(const bf16x8*)(As + (wr + i * 16 + m16) * 32 + quad * 8);
#pragma unroll
    for (int i = 0; i < 4; ++i)
      bfr[i] = *(const bf16x8*)(Bs + (wc + i * 16 + m16) * 32 + quad * 8);
#pragma unroll
    for (int i = 0; i < 4; ++i)
#pragma unroll
      for (int j = 0; j < 4; ++j)
        acc[i][j] = __builtin_amdgcn_mfma_f32_16x16x32_bf16(af[i], bfr[j], acc[i][j], 0, 0, 0);
  }

  // phase 1: C-frags -> LDS with bias/scale applied; 16B-group XOR swizzle by row&7
#pragma unroll
  for (int j = 0; j < 4; ++j) {
    const int col = wc + j * 16 + m16;            // 0..127
    const int gseg = (nb + col) >> 6;             // global 64-wide segment
    const int h = gseg / 3;
    const int which = gseg - 3 * h;
    const float bv = bias[nb + col];
    const float qs = (which == 0) ? 0.18033688011112042f : 1.0f;  // 0.125*log2(e)
#pragma unroll
    for (int i = 0; i < 4; ++i)
#pragma unroll
      for (int r = 0; r < 4; ++r) {
        const int row = wr + i * 16 + quad * 4 + r;
        const int sc = ((((col >> 3) ^ (row & 7)) << 3) | (col & 7));
        Cs[row * 128 + sc] = f2bf((acc[i][j][r] + bv) * qs);
      }
  }
  __syncthreads();

  // phase 2: thread t -> row t&127, segment t>>7; 8 b128 LDS reads + 8 b128 stores
  {
    const int row = t & 127, sSeg = t >> 7;       // wave-uniform sSeg
    const int seg = (nb >> 6) + sSeg;
    const int h = seg / 3, which = seg - h * 3;
    const int m = mb + row;
    const int b = m >> 11, sI = m & 2047;
    u16* dstP = (which == 0) ? Qp : (which == 1) ? Kp : Vp;
    u16* dst = dstP + (((size_t)((b << 4) | h)) * 2048 + sI) * 64;
    const int rx = row & 7;
#pragma unroll
    for (int k = 0; k < 8; ++k) {
      const int g = (sSeg * 8 + k) ^ rx;
      const bf16x8 v = *(const bf16x8*)(Cs + row * 128 + g * 8);
      *(bf16x8*)(dst + k * 8) = v;
    }
  }
}

// ---------------- out-proj GEMM: 64x128 tile + restaged f32 epilogue ---------------
__global__ __launch_bounds__(256) void gemm_out(
    const u16* __restrict__ A, const u16* __restrict__ Bt, const float* __restrict__ bias,
    float* __restrict__ Outp)
{
  const int Kd = 1024;
  __shared__ __align__(16) u16 As[64 * 32];
  __shared__ __align__(16) u16 Bs[128 * 32];
  __shared__ __align__(16) float Cf[64 * 128];
  const int t = threadIdx.x;
  const int lane = t & 63, wave = t >> 6;
  const int quad = lane >> 4, m16 = lane & 15;
  const int mb = blockIdx.y * 64, nb = blockIdx.x * 128;
  const int wr = (wave & 1) * 32, wc = (wave >> 1) * 64;

  const int srow = t >> 2;
  const int scol = (t & 3) * 8;
  const u16* Ag0 = A + (size_t)(mb + srow) * Kd + scol;
  const u16* Bg0 = Bt + (size_t)(nb + srow) * Kd + scol;
  const u16* Bg1 = Bg0 + (size_t)64 * Kd;
  u16* AsD = As + t * 8;
  u16* BsD = Bs + t * 8;

  f32x4 acc[2][4] = {};

  for (int k0 = 0; k0 < Kd; k0 += 32) {
    __syncthreads();
    async_load16(Ag0 + k0, AsD);
    async_load16(Bg0 + k0, BsD);
    async_load16(Bg1 + k0, BsD + 2048);
    __syncthreads();
    bf16x8 af[2], bfr[4];
#pragma unroll
    for (int i = 0; i < 2; ++i)
      af[i] = *(const bf16x8*)(As + (wr + i * 16 + m16) * 32 + quad * 8);
#pragma unroll
    for (int j = 0; j < 4; ++j)
      bfr[j] = *(const bf16x8*)(Bs + (wc + j * 16 + m16) * 32 + quad * 8);
#pragma unroll
    for (int i = 0; i < 2; ++i)
#pragma unroll
      for (int j = 0; j < 4; ++j)
        acc[i][j] = __builtin_amdgcn_mfma_f32_16x16x32_bf16(af[i], bfr[j], acc[i][j], 0, 0, 0);
  }

  // phase 1: restage f32 C-tile; 16B (4-float) group XOR swizzle by row&7
#pragma unroll
  for (int j = 0; j < 4; ++j) {
    const int col = wc + j * 16 + m16;            // 0..127
    const float bv = bias[nb + col];
#pragma unroll
    for (int i = 0; i < 2; ++i)
#pragma unroll
      for (int r = 0; r < 4; ++r) {
        const int row = wr + i * 16 + quad * 4 + r;   // 0..63
        const int sc = ((((col >> 2) ^ (row & 7)) << 2) | (col & 3));
        Cf[row * 128 + sc] = acc[i][j][r] + bv;
      }
  }
  __syncthreads();

  // phase 2: thread t -> row t&63, chunk t>>6; 8 b128 reads + 8 b128 stores (128B/thread)
  {
    const int row = t & 63, chunk = t >> 6;
    float* dst = Outp + (size_t)(mb + row) * 1024 + nb + chunk * 32;
    const int rx = row & 7;
#pragma unroll
    for (int k = 0; k < 8; ++k) {
      const int g = (chunk * 8 + k) ^ rx;
      const float4 v = *(const float4*)(Cf + row * 128 + g * 4);
      *(float4*)(dst + k * 4) = v;
    }
  }
}

// -------- flash attention v6: G=2 (32 q/wave), unroll-2 immediate LDS offsets ------
__global__ __launch_bounds__(256) void flash_attn(
    const u16* __restrict__ Q, const u16* __restrict__ K, const u16* __restrict__ Vt,
    u16* __restrict__ O)
{
  const int S = 2048;
  __shared__ __align__(16) u16 Kl[2][64 * 64];
  __shared__ __align__(16) u16 Vl[2][64 * 64];
  __shared__ __align__(16) u32 Pl[4][2][16 * 32];  // [wave][g][row m16(q)][32 u32]
  const int t = threadIdx.x;
  const int lane = t & 63, w = t >> 6;
  const int quad = lane >> 4, m16 = lane & 15;

  const int f = blockIdx.x;
  const int wi = f >> 3;                 // 0..63
  const int bh = (f & 7) + 8 * (wi & 3);
  const int q0 = (wi >> 2) * 128;

  const u16* Qb = Q + (size_t)bh * S * 64;
  const u16* Kb = K + (size_t)bh * S * 64;
  const u16* Vb = Vt + (size_t)bh * 64 * S;

  bf16x8 qf[2][2];
#pragma unroll
  for (int g = 0; g < 2; ++g)
#pragma unroll
    for (int ks = 0; ks < 2; ++ks)
      qf[g][ks] = *(const bf16x8*)(Qb + (size_t)(q0 + w * 32 + g * 16 + m16) * 64 + ks * 32 + quad * 8);

  const u16* Kg[2]; const u16* Vg[2]; int soff[2];
#pragma unroll
  for (int l = 0; l < 2; ++l) {
    const int idx = l * 256 + t;
    const int row = idx >> 3, slot = idx & 7;
    const int sg = slot ^ (row & 7);
    Kg[l] = Kb + row * 64 + sg * 8;
    Vg[l] = Vb + (size_t)row * S + sg * 8;
    soff[l] = idx * 8;
  }

  f32x4 ot[2][4] = {};
  f32x4 lr4[2] = {{0.f,0.f,0.f,0.f},{0.f,0.f,0.f,0.f}};
  u32* const Pw0 = &Pl[w][0][0];
  u32* const Pw1 = &Pl[w][1][0];

#define PREFETCH(kvp, B)                                                     \
  do {                                                                       \
    _Pragma("unroll")                                                        \
    for (int l = 0; l < 2; ++l) async_load16(Kg[l] + (kvp) * 64, &Kl[B][soff[l]]); \
    _Pragma("unroll")                                                        \
    for (int l = 0; l < 2; ++l) async_load16(Vg[l] + (kvp), &Vl[B][soff[l]]);      \
  } while (0)

#define STEP(B)                                                              \
  do {                                                                       \
    f32x4 st[2][4] = {};                                                     \
    _Pragma("unroll")                                                        \
    for (int nt = 0; nt < 4; ++nt) {                                         \
      const int j = nt * 16 + m16;                                           \
      const u16* rowp = &Kl[B][j * 64];                                      \
      const bf16x8 kb0 = *(const bf16x8*)(rowp + ((quad ^ (j & 7)) * 8));    \
      const bf16x8 kb1 = *(const bf16x8*)(rowp + (((4 + quad) ^ (j & 7)) * 8)); \
      st[0][nt] = __builtin_amdgcn_mfma_f32_16x16x32_bf16(kb0, qf[0][0], st[0][nt], 0, 0, 0); \
      st[1][nt] = __builtin_amdgcn_mfma_f32_16x16x32_bf16(kb0, qf[1][0], st[1][nt], 0, 0, 0); \
      st[0][nt] = __builtin_amdgcn_mfma_f32_16x16x32_bf16(kb1, qf[0][1], st[0][nt], 0, 0, 0); \
      st[1][nt] = __builtin_amdgcn_mfma_f32_16x16x32_bf16(kb1, qf[1][1], st[1][nt], 0, 0, 0); \
    }                                                                        \
    _Pragma("unroll")                                                        \
    for (int g = 0; g < 2; ++g) {                                            \
      u32* const Pw = g ? Pw1 : Pw0;                                         \
      _Pragma("unroll")                                                      \
      for (int nt = 0; nt < 4; ++nt) {                                       \
        f32x4 p;                                                             \
        _Pragma("unroll")                                                    \
        for (int r = 0; r < 4; ++r) p[r] = EXP2(st[g][nt][r]);               \
        lr4[g] += p;                                                         \
        const u32 lo = pk_bf16(p[0], p[1]);                                  \
        const u32 hi = pk_bf16(p[2], p[3]);                                  \
        const int gp = (2 * nt + (quad >> 1)) ^ (m16 & 7);                   \
        u32* dst = Pw + m16 * 32 + gp * 4 + (quad & 1) * 2;                  \
        *(uint2*)dst = make_uint2(lo, hi);                                   \
      }                                                                      \
    }                                                                        \
    _Pragma("unroll")                                                        \
    for (int ks = 0; ks < 2; ++ks) {                                         \
      const int pg = (ks * 4 + quad) ^ (m16 & 7);                            \
      const bf16x8 pb0 = *(const bf16x8*)(Pw0 + m16 * 32 + pg * 4);          \
      const bf16x8 pb1 = *(const bf16x8*)(Pw1 + m16 * 32 + pg * 4);          \
      _Pragma("unroll")                                                      \
      for (int dt = 0; dt < 4; ++dt) {                                       \
        const int d = dt * 16 + m16;                                         \
        const bf16x8 va = *(const bf16x8*)(&Vl[B][d * 64] + (((ks * 4 + quad) ^ (d & 7)) * 8)); \
        ot[0][dt] = __builtin_amdgcn_mfma_f32_16x16x32_bf16(va, pb0, ot[0][dt], 0, 0, 0); \
        ot[1][dt] = __builtin_amdgcn_mfma_f32_16x16x32_bf16(va, pb1, ot[1][dt], 0, 0, 0); \
      }                                                                      \
    }                                                                        \
  } while (0)

  PREFETCH(0, 0);
  __syncthreads();

  for (int kv0 = 0; kv0 < S; kv0 += 128) {
    PREFETCH(kv0 + 64, 1);
    STEP(0);
    __syncthreads();
    if (kv0 + 128 < S) PREFETCH(kv0 + 128, 0);
    STEP(1);
    __syncthreads();
  }
#undef PREFETCH
#undef STEP

  const int b = bh >> 4, h = bh & 15;
#pragma unroll
  for (int g = 0; g < 2; ++g) {
    float l = lr4[g][0] + lr4[g][1] + lr4[g][2] + lr4[g][3];
    l += __shfl_xor(l, 16, 64);
    l += __shfl_xor(l, 32, 64);
    const float inv = 1.0f / l;
    const int q = q0 + w * 32 + g * 16 + m16;
    u16* base = O + ((size_t)b * 2048 + q) * 1024 + h * 64;
#pragma unroll
    for (int dt = 0; dt < 4; ++dt) {
      const u32 lo = pk_bf16(ot[g][dt][0] * inv, ot[g][dt][1] * inv);
      const u32 hi = pk_bf16(ot[g][dt][2] * inv, ot[g][dt][3] * inv);
      *(uint2*)(base + dt * 16 + quad * 4) = make_uint2(lo, hi);
    }
  }
}

// ---------------- launch ----------------
extern "C" void kernel_launch(void* const* d_in, const int* in_sizes, int n_in,
                              void* d_out, int out_size, void* d_ws, size_t ws_size,
                              hipStream_t stream)
{
  const float* x     = (const float*)d_in[0];   // [2,2048,1024] f32
  const float* w_qkv = (const float*)d_in[1];   // [1024,3072]  f32
  const float* b_qkv = (const float*)d_in[2];   // [3072]       f32
  const float* w_out = (const float*)d_in[3];   // [1024,1024]  f32
  const float* b_out = (const float*)d_in[4];   // [1024]       f32
  float* out = (float*)d_out;                   // [2,2048,1024] f32

  u16* ws     = (u16*)d_ws;
  u16* xb     = ws;                          // [4096][1024] bf16
  u16* WtQKV  = xb + 4194304;                // [3072][1024] bf16
  u16* WtOut  = WtQKV + 3145728;             // [1024][1024] bf16
  u16* Qm     = WtOut + 1048576;             // [B,H,S,64]
  u16* Km     = Qm + 4194304;                // [B,H,S,64]
  u16* Vtm    = Km + 4194304;                // [B,H,64,S]
  u16* AO     = Vtm + 4194304;               // [B,S,E] bf16 (also scratch for plain V)
  u16* Vm     = AO;                          // plain V [B,H,S,64]; consumed before AO written

  preprocess<<<3072, 256, 0, stream>>>(x, xb, w_qkv, WtQKV, w_out, WtOut);
  gemm_qkv<<<dim3(24, 32), 256, 0, stream>>>(xb, WtQKV, b_qkv, Qm, Km, Vm, 1024);
  transpose_v<<<dim3(32, 32), 256, 0, stream>>>(Vm, Vtm);
  flash_attn<<<512, 256, 0, stream>>>(Qm, Km, Vtm, AO);
  gemm_out<<<dim3(8, 64), 256, 0, stream>>>(AO, WtOut, b_out, out);
}

// Round 10
// 193.704 us; speedup vs baseline: 1.0679x; 1.0679x over previous
//
#include <hip/hip_runtime.h>
#include <cstdint>

typedef unsigned short u16;
typedef unsigned int u32;
typedef __attribute__((ext_vector_type(8))) short bf16x8;   // 8 bf16 in 4 VGPRs
typedef __attribute__((ext_vector_type(4))) float f32x4;

#if __has_builtin(__builtin_amdgcn_exp2f)
#define EXP2(x) __builtin_amdgcn_exp2f(x)
#else
#define EXP2(x) exp2f(x)
#endif

__device__ __forceinline__ u16 f2bf(float f) {  // RNE
  unsigned u = __float_as_uint(f);
  u += 0x7fffu + ((u >> 16) & 1u);
  return (u16)(u >> 16);
}
__device__ __forceinline__ u32 pk_bf16(float lo, float hi) {  // RNE pack
#if __has_builtin(__builtin_amdgcn_cvt_pk_bf16_f32)
  auto r = __builtin_amdgcn_cvt_pk_bf16_f32(lo, hi);
  return __builtin_bit_cast(u32, r);
#else
  u32 a = __float_as_uint(lo), b = __float_as_uint(hi);
  a += 0x7fffu + ((a >> 16) & 1u);
  b += 0x7fffu + ((b >> 16) & 1u);
  return (a >> 16) | (b & 0xffff0000u);
#endif
}

// async global->LDS, 16B per lane. LDS dest must be wave-uniform base + lane*16.
__device__ __forceinline__ void async_load16(const void* g, void* l) {
  typedef const __attribute__((address_space(1))) void* gp_t;
  typedef __attribute__((address_space(3))) void* lp_t;
  __builtin_amdgcn_global_load_lds((gp_t)(uintptr_t)g, (lp_t)(uintptr_t)l, 16, 0, 0);
}

// ------- fused preprocess: x f32->bf16 copy (blocks [0,2048)) + both weight
//         transposes (blocks [2048,3072)) in ONE launch -------
__global__ __launch_bounds__(256) void preprocess(
    const float* __restrict__ x, u16* __restrict__ xb,
    const float* __restrict__ wqkv, u16* __restrict__ dqkv,
    const float* __restrict__ wout, u16* __restrict__ dout)
{
  __shared__ u16 tile[64][65];
  const int t = threadIdx.x;
  const int bx = blockIdx.x;
  if (bx < 2048) {
    const size_t i = ((size_t)bx * 256 + t) * 8;
    const float4 a = *(const float4*)(x + i);
    const float4 b = *(const float4*)(x + i + 4);
    union { u16 u[8]; bf16x8 v; } p;
    p.u[0] = f2bf(a.x); p.u[1] = f2bf(a.y); p.u[2] = f2bf(a.z); p.u[3] = f2bf(a.w);
    p.u[4] = f2bf(b.x); p.u[5] = f2bf(b.y); p.u[6] = f2bf(b.z); p.u[7] = f2bf(b.w);
    *(bf16x8*)(xb + i) = p.v;
    return;
  }
  const int tb = bx - 2048;            // 0..1023
  const int bxx = tb & 63, byy = tb >> 6;
  const bool isOut = bxx >= 48;
  const float* src = isOut ? wout : wqkv;
  u16* dst = isOut ? dout : dqkv;
  const int cols = isOut ? 1024 : 3072;
  const int rows = 1024;
  const int tc = (isOut ? (bxx - 48) : bxx) * 64;
  const int tr = byy * 64;
  const int r = t >> 2, c0 = (t & 3) * 16;
  const float* sp = src + (size_t)(tr + r) * cols + tc + c0;
#pragma unroll
  for (int i = 0; i < 16; i += 4) {
    const float4 v = *(const float4*)(sp + i);
    tile[r][c0 + i + 0] = f2bf(v.x);
    tile[r][c0 + i + 1] = f2bf(v.y);
    tile[r][c0 + i + 2] = f2bf(v.z);
    tile[r][c0 + i + 3] = f2bf(v.w);
  }
  __syncthreads();
  u16* dp = dst + (size_t)(tc + r) * rows + tr + c0;
#pragma unroll
  for (int i = 0; i < 16; ++i) dp[i] = tile[c0 + i][r];
}

// ------- batched V transpose: src [bh][2048][64] -> dst [bh][64][2048] (coalesced) ---
__global__ __launch_bounds__(256) void transpose_v(
    const u16* __restrict__ src, u16* __restrict__ dst)
{
  __shared__ u16 tile[64][72];
  const int t = threadIdx.x;
  const int r = t >> 2, c0 = (t & 3) * 16;
  const int bh = blockIdx.y, s0 = blockIdx.x * 64;
  const u16* sp = src + ((size_t)bh * 2048 + s0 + r) * 64 + c0;
  union { u16 u[8]; bf16x8 v; } a, b;
  a.v = *(const bf16x8*)sp;
  b.v = *(const bf16x8*)(sp + 8);
#pragma unroll
  for (int i = 0; i < 8; ++i) tile[r][c0 + i] = a.u[i];
#pragma unroll
  for (int i = 0; i < 8; ++i) tile[r][c0 + 8 + i] = b.u[i];
  __syncthreads();
  union { u16 u[8]; bf16x8 v; } x, y;
#pragma unroll
  for (int i = 0; i < 8; ++i) x.u[i] = tile[c0 + i][r];
#pragma unroll
  for (int i = 0; i < 8; ++i) y.u[i] = tile[c0 + 8 + i][r];
  u16* dp = dst + ((size_t)bh * 64 + r) * 2048 + s0 + c0;
  *(bf16x8*)dp = x.v;
  *(bf16x8*)(dp + 8) = y.v;
}

// ---------------- QKV GEMM v2: double-buffered, ONE barrier per K-step -------------
// C[m][n] = sum_k A[m][k]*Bt[n][k] + bias[n]; n = h*192+which*64+d.
// Prefetch of tile k+1 is issued BEFORE computing tile k; the compiler's
// vmcnt(0)-before-barrier drain lands after the 16 MFMAs (latency hidden).
__global__ __launch_bounds__(256) void gemm_qkv(
    const u16* __restrict__ A, const u16* __restrict__ Bt, const float* __restrict__ bias,
    u16* __restrict__ Qp, u16* __restrict__ Kp, u16* __restrict__ Vp)
{
  const int Kd = 1024;
  __shared__ __align__(16) u16 As[2][128 * 32];
  __shared__ __align__(16) u16 Bs[2][128 * 32];
  const int t = threadIdx.x;
  const int lane = t & 63, wave = t >> 6;
  const int quad = lane >> 4, m16 = lane & 15;
  const int mb = blockIdx.y * 128, nb = blockIdx.x * 128;
  const int wr = (wave & 1) * 64, wc = (wave >> 1) * 64;

  const int srow = t >> 2;
  const int scol = (t & 3) * 8;
  const u16* Ag0 = A + (size_t)(mb + srow) * Kd + scol;
  const u16* Ag1 = Ag0 + (size_t)64 * Kd;
  const u16* Bg0 = Bt + (size_t)(nb + srow) * Kd + scol;
  const u16* Bg1 = Bg0 + (size_t)64 * Kd;
  const int aoff = t * 8;

  f32x4 acc[4][4] = {};

#define GPRE(k0, B)                                                          \
  do {                                                                       \
    async_load16(Ag0 + (k0), &As[B][aoff]);                                  \
    async_load16(Ag1 + (k0), &As[B][aoff + 2048]);                           \
    async_load16(Bg0 + (k0), &Bs[B][aoff]);                                  \
    async_load16(Bg1 + (k0), &Bs[B][aoff + 2048]);                           \
  } while (0)

#define GSTEP(B)                                                             \
  do {                                                                       \
    bf16x8 af[4], bfr[4];                                                    \
    _Pragma("unroll")                                                        \
    for (int i = 0; i < 4; ++i)                                              \
      af[i] = *(const bf16x8*)(&As[B][(wr + i * 16 + m16) * 32 + quad * 8]); \
    _Pragma("unroll")                                                        \
    for (int i = 0; i < 4; ++i)                                              \
      bfr[i] = *(const bf16x8*)(&Bs[B][(wc + i * 16 + m16) * 32 + quad * 8]); \
    _Pragma("unroll")                                                        \
    for (int i = 0; i < 4; ++i)                                              \
      _Pragma("unroll")                                                      \
      for (int j = 0; j < 4; ++j)                                            \
        acc[i][j] = __builtin_amdgcn_mfma_f32_16x16x32_bf16(af[i], bfr[j], acc[i][j], 0, 0, 0); \
  } while (0)

  GPRE(0, 0);
  __syncthreads();
  for (int k0 = 0; k0 < Kd; k0 += 64) {
    GPRE(k0 + 32, 1);                // always valid (k0+32 <= 992)
    GSTEP(0);
    __syncthreads();
    if (k0 + 64 < Kd) GPRE(k0 + 64, 0);
    GSTEP(1);
    __syncthreads();
  }
#undef GPRE
#undef GSTEP

  // direct-store epilogue (round-8 form; measured better than LDS restage)
#pragma unroll
  for (int j = 0; j < 4; ++j) {
    const int base = nb + wc + j * 16;
    const float bv = bias[base + m16];
    const int seg = base >> 6;                  // = h*3 + which (wave-uniform)
    const int h = seg / 3;
    const int which = seg - h * 3;
    const int d = (base & 63) + m16;
    const float qs = (which == 0) ? 0.18033688011112042f : 1.0f;  // 0.125*log2(e)
#pragma unroll
    for (int i = 0; i < 4; ++i)
#pragma unroll
      for (int r = 0; r < 4; ++r) {
        const int row = mb + wr + i * 16 + quad * 4 + r;
        const int b = row >> 11, sI = row & 2047;
        const u16 v = f2bf((acc[i][j][r] + bv) * qs);
        const size_t idx = (((size_t)((b << 4) | h)) * 2048 + sI) * 64 + d;
        if (which == 0)      Qp[idx] = v;
        else if (which == 1) Kp[idx] = v;
        else                 Vp[idx] = v;     // plain, coalesced; transposed later
      }
  }
}

// ---------------- out-proj GEMM v2: 64x128 tile, double-buffered, 1 barrier/step ---
__global__ __launch_bounds__(256) void gemm_out(
    const u16* __restrict__ A, const u16* __restrict__ Bt, const float* __restrict__ bias,
    float* __restrict__ Outp)
{
  const int Kd = 1024;
  __shared__ __align__(16) u16 As[2][64 * 32];
  __shared__ __align__(16) u16 Bs[2][128 * 32];
  const int t = threadIdx.x;
  const int lane = t & 63, wave = t >> 6;
  const int quad = lane >> 4, m16 = lane & 15;
  const int mb = blockIdx.y * 64, nb = blockIdx.x * 128;
  const int wr = (wave & 1) * 32, wc = (wave >> 1) * 64;

  const int srow = t >> 2;
  const int scol = (t & 3) * 8;
  const u16* Ag0 = A + (size_t)(mb + srow) * Kd + scol;
  const u16* Bg0 = Bt + (size_t)(nb + srow) * Kd + scol;
  const u16* Bg1 = Bg0 + (size_t)64 * Kd;
  const int aoff = t * 8;

  f32x4 acc[2][4] = {};

#define OPRE(k0, B)                                                          \
  do {                                                                       \
    async_load16(Ag0 + (k0), &As[B][aoff]);                                  \
    async_load16(Bg0 + (k0), &Bs[B][aoff]);                                  \
    async_load16(Bg1 + (k0), &Bs[B][aoff + 2048]);                           \
  } while (0)

#define OSTEP(B)                                                             \
  do {                                                                       \
    bf16x8 af[2], bfr[4];                                                    \
    _Pragma("unroll")                                                        \
    for (int i = 0; i < 2; ++i)                                              \
      af[i] = *(const bf16x8*)(&As[B][(wr + i * 16 + m16) * 32 + quad * 8]); \
    _Pragma("unroll")                                                        \
    for (int j = 0; j < 4; ++j)                                              \
      bfr[j] = *(const bf16x8*)(&Bs[B][(wc + j * 16 + m16) * 32 + quad * 8]); \
    _Pragma("unroll")                                                        \
    for (int i = 0; i < 2; ++i)                                              \
      _Pragma("unroll")                                                      \
      for (int j = 0; j < 4; ++j)                                            \
        acc[i][j] = __builtin_amdgcn_mfma_f32_16x16x32_bf16(af[i], bfr[j], acc[i][j], 0, 0, 0); \
  } while (0)

  OPRE(0, 0);
  __syncthreads();
  for (int k0 = 0; k0 < Kd; k0 += 64) {
    OPRE(k0 + 32, 1);
    OSTEP(0);
    __syncthreads();
    if (k0 + 64 < Kd) OPRE(k0 + 64, 0);
    OSTEP(1);
    __syncthreads();
  }
#undef OPRE
#undef OSTEP

#pragma unroll
  for (int j = 0; j < 4; ++j) {
    const int col = nb + wc + j * 16 + m16;
    const float bv = bias[col];
#pragma unroll
    for (int i = 0; i < 2; ++i)
#pragma unroll
      for (int r = 0; r < 4; ++r) {
        const int row = mb + wr + i * 16 + quad * 4 + r;
        Outp[(size_t)row * 1024 + col] = acc[i][j][r] + bv;
      }
  }
}

// -------- flash attention v6: G=2 (32 q/wave), unroll-2 immediate LDS offsets ------
__global__ __launch_bounds__(256) void flash_attn(
    const u16* __restrict__ Q, const u16* __restrict__ K, const u16* __restrict__ Vt,
    u16* __restrict__ O)
{
  const int S = 2048;
  __shared__ __align__(16) u16 Kl[2][64 * 64];
  __shared__ __align__(16) u16 Vl[2][64 * 64];
  __shared__ __align__(16) u32 Pl[4][2][16 * 32];  // [wave][g][row m16(q)][32 u32]
  const int t = threadIdx.x;
  const int lane = t & 63, w = t >> 6;
  const int quad = lane >> 4, m16 = lane & 15;

  const int f = blockIdx.x;
  const int wi = f >> 3;                 // 0..63
  const int bh = (f & 7) + 8 * (wi & 3);
  const int q0 = (wi >> 2) * 128;

  const u16* Qb = Q + (size_t)bh * S * 64;
  const u16* Kb = K + (size_t)bh * S * 64;
  const u16* Vb = Vt + (size_t)bh * 64 * S;

  bf16x8 qf[2][2];
#pragma unroll
  for (int g = 0; g < 2; ++g)
#pragma unroll
    for (int ks = 0; ks < 2; ++ks)
      qf[g][ks] = *(const bf16x8*)(Qb + (size_t)(q0 + w * 32 + g * 16 + m16) * 64 + ks * 32 + quad * 8);

  const u16* Kg[2]; const u16* Vg[2]; int soff[2];
#pragma unroll
  for (int l = 0; l < 2; ++l) {
    const int idx = l * 256 + t;
    const int row = idx >> 3, slot = idx & 7;
    const int sg = slot ^ (row & 7);
    Kg[l] = Kb + row * 64 + sg * 8;
    Vg[l] = Vb + (size_t)row * S + sg * 8;
    soff[l] = idx * 8;
  }

  f32x4 ot[2][4] = {};
  f32x4 lr4[2] = {{0.f,0.f,0.f,0.f},{0.f,0.f,0.f,0.f}};
  u32* const Pw0 = &Pl[w][0][0];
  u32* const Pw1 = &Pl[w][1][0];

#define PREFETCH(kvp, B)                                                     \
  do {                                                                       \
    _Pragma("unroll")                                                        \
    for (int l = 0; l < 2; ++l) async_load16(Kg[l] + (kvp) * 64, &Kl[B][soff[l]]); \
    _Pragma("unroll")                                                        \
    for (int l = 0; l < 2; ++l) async_load16(Vg[l] + (kvp), &Vl[B][soff[l]]);      \
  } while (0)

#define STEP(B)                                                              \
  do {                                                                       \
    f32x4 st[2][4] = {};                                                     \
    _Pragma("unroll")                                                        \
    for (int nt = 0; nt < 4; ++nt) {                                         \
      const int j = nt * 16 + m16;                                           \
      const u16* rowp = &Kl[B][j * 64];                                      \
      const bf16x8 kb0 = *(const bf16x8*)(rowp + ((quad ^ (j & 7)) * 8));    \
      const bf16x8 kb1 = *(const bf16x8*)(rowp + (((4 + quad) ^ (j & 7)) * 8)); \
      st[0][nt] = __builtin_amdgcn_mfma_f32_16x16x32_bf16(kb0, qf[0][0], st[0][nt], 0, 0, 0); \
      st[1][nt] = __builtin_amdgcn_mfma_f32_16x16x32_bf16(kb0, qf[1][0], st[1][nt], 0, 0, 0); \
      st[0][nt] = __builtin_amdgcn_mfma_f32_16x16x32_bf16(kb1, qf[0][1], st[0][nt], 0, 0, 0); \
      st[1][nt] = __builtin_amdgcn_mfma_f32_16x16x32_bf16(kb1, qf[1][1], st[1][nt], 0, 0, 0); \
    }                                                                        \
    _Pragma("unroll")                                                        \
    for (int g = 0; g < 2; ++g) {                                            \
      u32* const Pw = g ? Pw1 : Pw0;                                         \
      _Pragma("unroll")                                                      \
      for (int nt = 0; nt < 4; ++nt) {                                       \
        f32x4 p;                                                             \
        _Pragma("unroll")                                                    \
        for (int r = 0; r < 4; ++r) p[r] = EXP2(st[g][nt][r]);               \
        lr4[g] += p;                                                         \
        const u32 lo = pk_bf16(p[0], p[1]);                                  \
        const u32 hi = pk_bf16(p[2], p[3]);                                  \
        const int gp = (2 * nt + (quad >> 1)) ^ (m16 & 7);                   \
        u32* dst = Pw + m16 * 32 + gp * 4 + (quad & 1) * 2;                  \
        *(uint2*)dst = make_uint2(lo, hi);                                   \
      }                                                                      \
    }                                                                        \
    _Pragma("unroll")                                                        \
    for (int ks = 0; ks < 2; ++ks) {                                         \
      const int pg = (ks * 4 + quad) ^ (m16 & 7);                            \
      const bf16x8 pb0 = *(const bf16x8*)(Pw0 + m16 * 32 + pg * 4);          \
      const bf16x8 pb1 = *(const bf16x8*)(Pw1 + m16 * 32 + pg * 4);          \
      _Pragma("unroll")                                                      \
      for (int dt = 0; dt < 4; ++dt) {                                       \
        const int d = dt * 16 + m16;                                         \
        const bf16x8 va = *(const bf16x8*)(&Vl[B][d * 64] + (((ks * 4 + quad) ^ (d & 7)) * 8)); \
        ot[0][dt] = __builtin_amdgcn_mfma_f32_16x16x32_bf16(va, pb0, ot[0][dt], 0, 0, 0); \
        ot[1][dt] = __builtin_amdgcn_mfma_f32_16x16x32_bf16(va, pb1, ot[1][dt], 0, 0, 0); \
      }                                                                      \
    }                                                                        \
  } while (0)

  PREFETCH(0, 0);
  __syncthreads();

  for (int kv0 = 0; kv0 < S; kv0 += 128) {
    PREFETCH(kv0 + 64, 1);
    STEP(0);
    __syncthreads();
    if (kv0 + 128 < S) PREFETCH(kv0 + 128, 0);
    STEP(1);
    __syncthreads();
  }
#undef PREFETCH
#undef STEP

  const int b = bh >> 4, h = bh & 15;
#pragma unroll
  for (int g = 0; g < 2; ++g) {
    float l = lr4[g][0] + lr4[g][1] + lr4[g][2] + lr4[g][3];
    l += __shfl_xor(l, 16, 64);
    l += __shfl_xor(l, 32, 64);
    const float inv = 1.0f / l;
    const int q = q0 + w * 32 + g * 16 + m16;
    u16* base = O + ((size_t)b * 2048 + q) * 1024 + h * 64;
#pragma unroll
    for (int dt = 0; dt < 4; ++dt) {
      const u32 lo = pk_bf16(ot[g][dt][0] * inv, ot[g][dt][1] * inv);
      const u32 hi = pk_bf16(ot[g][dt][2] * inv, ot[g][dt][3] * inv);
      *(uint2*)(base + dt * 16 + quad * 4) = make_uint2(lo, hi);
    }
  }
}

// ---------------- launch ----------------
extern "C" void kernel_launch(void* const* d_in, const int* in_sizes, int n_in,
                              void* d_out, int out_size, void* d_ws, size_t ws_size,
                              hipStream_t stream)
{
  const float* x     = (const float*)d_in[0];   // [2,2048,1024] f32
  const float* w_qkv = (const float*)d_in[1];   // [1024,3072]  f32
  const float* b_qkv = (const float*)d_in[2];   // [3072]       f32
  const float* w_out = (const float*)d_in[3];   // [1024,1024]  f32
  const float* b_out = (const float*)d_in[4];   // [1024]       f32
  float* out = (float*)d_out;                   // [2,2048,1024] f32

  u16* ws     = (u16*)d_ws;
  u16* xb     = ws;                          // [4096][1024] bf16
  u16* WtQKV  = xb + 4194304;                // [3072][1024] bf16
  u16* WtOut  = WtQKV + 3145728;             // [1024][1024] bf16
  u16* Qm     = WtOut + 1048576;             // [B,H,S,64]
  u16* Km     = Qm + 4194304;                // [B,H,S,64]
  u16* Vtm    = Km + 4194304;                // [B,H,64,S]
  u16* AO     = Vtm + 4194304;               // [B,S,E] bf16 (also scratch for plain V)
  u16* Vm     = AO;                          // plain V [B,H,S,64]; consumed before AO written

  preprocess<<<3072, 256, 0, stream>>>(x, xb, w_qkv, WtQKV, w_out, WtOut);
  gemm_qkv<<<dim3(24, 32), 256, 0, stream>>>(xb, WtQKV, b_qkv, Qm, Km, Vm);
  transpose_v<<<dim3(32, 32), 256, 0, stream>>>(Vm, Vtm);
  flash_attn<<<512, 256, 0, stream>>>(Qm, Km, Vtm, AO);
  gemm_out<<<dim3(8, 64), 256, 0, stream>>>(AO, WtOut, b_out, out);
}

// Round 11
// 193.213 us; speedup vs baseline: 1.0706x; 1.0025x over previous
//
#include <hip/hip_runtime.h>
#include <cstdint>

typedef unsigned short u16;
typedef unsigned int u32;
typedef __attribute__((ext_vector_type(8))) short bf16x8;   // 8 bf16 in 4 VGPRs
typedef __attribute__((ext_vector_type(4))) float f32x4;

#if __has_builtin(__builtin_amdgcn_exp2f)
#define EXP2(x) __builtin_amdgcn_exp2f(x)
#else
#define EXP2(x) exp2f(x)
#endif

__device__ __forceinline__ u16 f2bf(float f) {  // RNE
  unsigned u = __float_as_uint(f);
  u += 0x7fffu + ((u >> 16) & 1u);
  return (u16)(u >> 16);
}
__device__ __forceinline__ u32 pk_bf16(float lo, float hi) {  // RNE pack
#if __has_builtin(__builtin_amdgcn_cvt_pk_bf16_f32)
  auto r = __builtin_amdgcn_cvt_pk_bf16_f32(lo, hi);
  return __builtin_bit_cast(u32, r);
#else
  u32 a = __float_as_uint(lo), b = __float_as_uint(hi);
  a += 0x7fffu + ((a >> 16) & 1u);
  b += 0x7fffu + ((b >> 16) & 1u);
  return (a >> 16) | (b & 0xffff0000u);
#endif
}

// async global->LDS, 16B per lane. LDS dest must be wave-uniform base + lane*16.
__device__ __forceinline__ void async_load16(const void* g, void* l) {
  typedef const __attribute__((address_space(1))) void* gp_t;
  typedef __attribute__((address_space(3))) void* lp_t;
  __builtin_amdgcn_global_load_lds((gp_t)(uintptr_t)g, (lp_t)(uintptr_t)l, 16, 0, 0);
}

// ------- fused preprocess: x f32->bf16 copy (blocks [0,2048)) + both weight
//         transposes (blocks [2048,3072)) in ONE launch -------
__global__ __launch_bounds__(256) void preprocess(
    const float* __restrict__ x, u16* __restrict__ xb,
    const float* __restrict__ wqkv, u16* __restrict__ dqkv,
    const float* __restrict__ wout, u16* __restrict__ dout)
{
  __shared__ u16 tile[64][65];
  const int t = threadIdx.x;
  const int bx = blockIdx.x;
  if (bx < 2048) {
    const size_t i = ((size_t)bx * 256 + t) * 8;
    const float4 a = *(const float4*)(x + i);
    const float4 b = *(const float4*)(x + i + 4);
    union { u16 u[8]; bf16x8 v; } p;
    p.u[0] = f2bf(a.x); p.u[1] = f2bf(a.y); p.u[2] = f2bf(a.z); p.u[3] = f2bf(a.w);
    p.u[4] = f2bf(b.x); p.u[5] = f2bf(b.y); p.u[6] = f2bf(b.z); p.u[7] = f2bf(b.w);
    *(bf16x8*)(xb + i) = p.v;
    return;
  }
  const int tb = bx - 2048;            // 0..1023
  const int bxx = tb & 63, byy = tb >> 6;
  const bool isOut = bxx >= 48;
  const float* src = isOut ? wout : wqkv;
  u16* dst = isOut ? dout : dqkv;
  const int cols = isOut ? 1024 : 3072;
  const int rows = 1024;
  const int tc = (isOut ? (bxx - 48) : bxx) * 64;
  const int tr = byy * 64;
  const int r = t >> 2, c0 = (t & 3) * 16;
  const float* sp = src + (size_t)(tr + r) * cols + tc + c0;
#pragma unroll
  for (int i = 0; i < 16; i += 4) {
    const float4 v = *(const float4*)(sp + i);
    tile[r][c0 + i + 0] = f2bf(v.x);
    tile[r][c0 + i + 1] = f2bf(v.y);
    tile[r][c0 + i + 2] = f2bf(v.z);
    tile[r][c0 + i + 3] = f2bf(v.w);
  }
  __syncthreads();
  u16* dp = dst + (size_t)(tc + r) * rows + tr + c0;
#pragma unroll
  for (int i = 0; i < 16; ++i) dp[i] = tile[c0 + i][r];
}

// ---------------- QKV GEMM v3: double-buffered + direct-Vt epilogue ----------------
// C[m][n] = sum_k A[m][k]*Bt[n][k] + bias[n]; n = h*192+which*64+d.
// Each wave's 64-col half aligns with ONE segment -> `which` is wave-uniform.
// Q/K waves: normal mfma(af,bfr) -> rows s, coalesced-ish [s][d] stores.
// V waves: OPERAND-SWAPPED mfma(bfr,af) -> C^T in registers (row d, col s):
// stores go straight into Vt [bh][64 d][2048 s] -- transpose_v kernel eliminated.
__global__ __launch_bounds__(256) void gemm_qkv(
    const u16* __restrict__ A, const u16* __restrict__ Bt, const float* __restrict__ bias,
    u16* __restrict__ Qp, u16* __restrict__ Kp, u16* __restrict__ Vtp)
{
  const int Kd = 1024;
  __shared__ __align__(16) u16 As[2][128 * 32];
  __shared__ __align__(16) u16 Bs[2][128 * 32];
  const int t = threadIdx.x;
  const int lane = t & 63, wave = t >> 6;
  const int quad = lane >> 4, m16 = lane & 15;
  const int mb = blockIdx.y * 128, nb = blockIdx.x * 128;
  const int wr = (wave & 1) * 64, wc = (wave >> 1) * 64;

  // wave-uniform segment decode
  const int seg = (nb + wc) >> 6;          // = h*3 + which
  const int h = seg / 3;
  const int which = seg - 3 * h;
  const bool isV = (which == 2);

  const int srow = t >> 2;
  const int scol = (t & 3) * 8;
  const u16* Ag0 = A + (size_t)(mb + srow) * Kd + scol;
  const u16* Ag1 = Ag0 + (size_t)64 * Kd;
  const u16* Bg0 = Bt + (size_t)(nb + srow) * Kd + scol;
  const u16* Bg1 = Bg0 + (size_t)64 * Kd;
  const int aoff = t * 8;

  f32x4 acc[4][4] = {};

#define GPRE(k0, B)                                                          \
  do {                                                                       \
    async_load16(Ag0 + (k0), &As[B][aoff]);                                  \
    async_load16(Ag1 + (k0), &As[B][aoff + 2048]);                           \
    async_load16(Bg0 + (k0), &Bs[B][aoff]);                                  \
    async_load16(Bg1 + (k0), &Bs[B][aoff + 2048]);                           \
  } while (0)

#define GSTEP(B)                                                             \
  do {                                                                       \
    bf16x8 af[4], bfr[4];                                                    \
    _Pragma("unroll")                                                        \
    for (int i = 0; i < 4; ++i)                                              \
      af[i] = *(const bf16x8*)(&As[B][(wr + i * 16 + m16) * 32 + quad * 8]); \
    _Pragma("unroll")                                                        \
    for (int i = 0; i < 4; ++i)                                              \
      bfr[i] = *(const bf16x8*)(&Bs[B][(wc + i * 16 + m16) * 32 + quad * 8]); \
    if (isV) {                                                               \
      _Pragma("unroll")                                                      \
      for (int i = 0; i < 4; ++i)                                            \
        _Pragma("unroll")                                                    \
        for (int j = 0; j < 4; ++j)                                          \
          acc[i][j] = __builtin_amdgcn_mfma_f32_16x16x32_bf16(bfr[i], af[j], acc[i][j], 0, 0, 0); \
    } else {                                                                 \
      _Pragma("unroll")                                                      \
      for (int i = 0; i < 4; ++i)                                            \
        _Pragma("unroll")                                                    \
        for (int j = 0; j < 4; ++j)                                          \
          acc[i][j] = __builtin_amdgcn_mfma_f32_16x16x32_bf16(af[i], bfr[j], acc[i][j], 0, 0, 0); \
    }                                                                        \
  } while (0)

  GPRE(0, 0);
  __syncthreads();
  for (int k0 = 0; k0 < Kd; k0 += 64) {
    GPRE(k0 + 32, 1);                // always valid (k0+32 <= 992)
    GSTEP(0);
    __syncthreads();
    if (k0 + 64 < Kd) GPRE(k0 + 64, 0);
    GSTEP(1);
    __syncthreads();
  }
#undef GPRE
#undef GSTEP

  const int b = mb >> 11;                  // block rows stay in one batch
  const size_t bh64 = (size_t)((b << 4) | h);

  if (isV) {
    // acc[i][j] = C^T tile: row d = i*16+quad*4+r, col s = mb+wr+j*16+m16
    const int sIbase = (mb & 2047) + wr;
    u16* dstV = Vtp + bh64 * 64 * 2048;
#pragma unroll
    for (int i = 0; i < 4; ++i)
#pragma unroll
      for (int r = 0; r < 4; ++r) {
        const int d = i * 16 + quad * 4 + r;
        const float bv = bias[nb + wc + d];
        u16* rp = dstV + (size_t)d * 2048 + sIbase;
#pragma unroll
        for (int j = 0; j < 4; ++j)
          rp[j * 16 + m16] = f2bf(acc[i][j][r] + bv);
      }
  } else {
    u16* dstP = (which == 0) ? Qp : Kp;
    const float qs = (which == 0) ? 0.18033688011112042f : 1.0f;  // 0.125*log2(e)
#pragma unroll
    for (int j = 0; j < 4; ++j) {
      const int base = nb + wc + j * 16;
      const float bv = bias[base + m16];
      const int d = (base & 63) + m16;     // = j*16 + m16
#pragma unroll
      for (int i = 0; i < 4; ++i)
#pragma unroll
        for (int r = 0; r < 4; ++r) {
          const int row = mb + wr + i * 16 + quad * 4 + r;
          const int sI = row & 2047;
          dstP[(bh64 * 2048 + sI) * 64 + d] = f2bf((acc[i][j][r] + bv) * qs);
        }
    }
  }
}

// ---------------- out-proj GEMM v2: 64x128 tile, double-buffered, 1 barrier/step ---
__global__ __launch_bounds__(256) void gemm_out(
    const u16* __restrict__ A, const u16* __restrict__ Bt, const float* __restrict__ bias,
    float* __restrict__ Outp)
{
  const int Kd = 1024;
  __shared__ __align__(16) u16 As[2][64 * 32];
  __shared__ __align__(16) u16 Bs[2][128 * 32];
  const int t = threadIdx.x;
  const int lane = t & 63, wave = t >> 6;
  const int quad = lane >> 4, m16 = lane & 15;
  const int mb = blockIdx.y * 64, nb = blockIdx.x * 128;
  const int wr = (wave & 1) * 32, wc = (wave >> 1) * 64;

  const int srow = t >> 2;
  const int scol = (t & 3) * 8;
  const u16* Ag0 = A + (size_t)(mb + srow) * Kd + scol;
  const u16* Bg0 = Bt + (size_t)(nb + srow) * Kd + scol;
  const u16* Bg1 = Bg0 + (size_t)64 * Kd;
  const int aoff = t * 8;

  f32x4 acc[2][4] = {};

#define OPRE(k0, B)                                                          \
  do {                                                                       \
    async_load16(Ag0 + (k0), &As[B][aoff]);                                  \
    async_load16(Bg0 + (k0), &Bs[B][aoff]);                                  \
    async_load16(Bg1 + (k0), &Bs[B][aoff + 2048]);                           \
  } while (0)

#define OSTEP(B)                                                             \
  do {                                                                       \
    bf16x8 af[2], bfr[4];                                                    \
    _Pragma("unroll")                                                        \
    for (int i = 0; i < 2; ++i)                                              \
      af[i] = *(const bf16x8*)(&As[B][(wr + i * 16 + m16) * 32 + quad * 8]); \
    _Pragma("unroll")                                                        \
    for (int j = 0; j < 4; ++j)                                              \
      bfr[j] = *(const bf16x8*)(&Bs[B][(wc + j * 16 + m16) * 32 + quad * 8]); \
    _Pragma("unroll")                                                        \
    for (int i = 0; i < 2; ++i)                                              \
      _Pragma("unroll")                                                      \
      for (int j = 0; j < 4; ++j)                                            \
        acc[i][j] = __builtin_amdgcn_mfma_f32_16x16x32_bf16(af[i], bfr[j], acc[i][j], 0, 0, 0); \
  } while (0)

  OPRE(0, 0);
  __syncthreads();
  for (int k0 = 0; k0 < Kd; k0 += 64) {
    OPRE(k0 + 32, 1);
    OSTEP(0);
    __syncthreads();
    if (k0 + 64 < Kd) OPRE(k0 + 64, 0);
    OSTEP(1);
    __syncthreads();
  }
#undef OPRE
#undef OSTEP

#pragma unroll
  for (int j = 0; j < 4; ++j) {
    const int col = nb + wc + j * 16 + m16;
    const float bv = bias[col];
#pragma unroll
    for (int i = 0; i < 2; ++i)
#pragma unroll
      for (int r = 0; r < 4; ++r) {
        const int row = mb + wr + i * 16 + quad * 4 + r;
        Outp[(size_t)row * 1024 + col] = acc[i][j][r] + bv;
      }
  }
}

// -------- flash attention v6: G=2 (32 q/wave), unroll-2 immediate LDS offsets ------
__global__ __launch_bounds__(256) void flash_attn(
    const u16* __restrict__ Q, const u16* __restrict__ K, const u16* __restrict__ Vt,
    u16* __restrict__ O)
{
  const int S = 2048;
  __shared__ __align__(16) u16 Kl[2][64 * 64];
  __shared__ __align__(16) u16 Vl[2][64 * 64];
  __shared__ __align__(16) u32 Pl[4][2][16 * 32];  // [wave][g][row m16(q)][32 u32]
  const int t = threadIdx.x;
  const int lane = t & 63, w = t >> 6;
  const int quad = lane >> 4, m16 = lane & 15;

  const int f = blockIdx.x;
  const int wi = f >> 3;                 // 0..63
  const int bh = (f & 7) + 8 * (wi & 3);
  const int q0 = (wi >> 2) * 128;

  const u16* Qb = Q + (size_t)bh * S * 64;
  const u16* Kb = K + (size_t)bh * S * 64;
  const u16* Vb = Vt + (size_t)bh * 64 * S;

  bf16x8 qf[2][2];
#pragma unroll
  for (int g = 0; g < 2; ++g)
#pragma unroll
    for (int ks = 0; ks < 2; ++ks)
      qf[g][ks] = *(const bf16x8*)(Qb + (size_t)(q0 + w * 32 + g * 16 + m16) * 64 + ks * 32 + quad * 8);

  const u16* Kg[2]; const u16* Vg[2]; int soff[2];
#pragma unroll
  for (int l = 0; l < 2; ++l) {
    const int idx = l * 256 + t;
    const int row = idx >> 3, slot = idx & 7;
    const int sg = slot ^ (row & 7);
    Kg[l] = Kb + row * 64 + sg * 8;
    Vg[l] = Vb + (size_t)row * S + sg * 8;
    soff[l] = idx * 8;
  }

  f32x4 ot[2][4] = {};
  f32x4 lr4[2] = {{0.f,0.f,0.f,0.f},{0.f,0.f,0.f,0.f}};
  u32* const Pw0 = &Pl[w][0][0];
  u32* const Pw1 = &Pl[w][1][0];

#define PREFETCH(kvp, B)                                                     \
  do {                                                                       \
    _Pragma("unroll")                                                        \
    for (int l = 0; l < 2; ++l) async_load16(Kg[l] + (kvp) * 64, &Kl[B][soff[l]]); \
    _Pragma("unroll")                                                        \
    for (int l = 0; l < 2; ++l) async_load16(Vg[l] + (kvp), &Vl[B][soff[l]]);      \
  } while (0)

#define STEP(B)                                                              \
  do {                                                                       \
    f32x4 st[2][4] = {};                                                     \
    _Pragma("unroll")                                                        \
    for (int nt = 0; nt < 4; ++nt) {                                         \
      const int j = nt * 16 + m16;                                           \
      const u16* rowp = &Kl[B][j * 64];                                      \
      const bf16x8 kb0 = *(const bf16x8*)(rowp + ((quad ^ (j & 7)) * 8));    \
      const bf16x8 kb1 = *(const bf16x8*)(rowp + (((4 + quad) ^ (j & 7)) * 8)); \
      st[0][nt] = __builtin_amdgcn_mfma_f32_16x16x32_bf16(kb0, qf[0][0], st[0][nt], 0, 0, 0); \
      st[1][nt] = __builtin_amdgcn_mfma_f32_16x16x32_bf16(kb0, qf[1][0], st[1][nt], 0, 0, 0); \
      st[0][nt] = __builtin_amdgcn_mfma_f32_16x16x32_bf16(kb1, qf[0][1], st[0][nt], 0, 0, 0); \
      st[1][nt] = __builtin_amdgcn_mfma_f32_16x16x32_bf16(kb1, qf[1][1], st[1][nt], 0, 0, 0); \
    }                                                                        \
    _Pragma("unroll")                                                        \
    for (int g = 0; g < 2; ++g) {                                            \
      u32* const Pw = g ? Pw1 : Pw0;                                         \
      _Pragma("unroll")                                                      \
      for (int nt = 0; nt < 4; ++nt) {                                       \
        f32x4 p;                                                             \
        _Pragma("unroll")                                                    \
        for (int r = 0; r < 4; ++r) p[r] = EXP2(st[g][nt][r]);               \
        lr4[g] += p;                                                         \
        const u32 lo = pk_bf16(p[0], p[1]);                                  \
        const u32 hi = pk_bf16(p[2], p[3]);                                  \
        const int gp = (2 * nt + (quad >> 1)) ^ (m16 & 7);                   \
        u32* dst = Pw + m16 * 32 + gp * 4 + (quad & 1) * 2;                  \
        *(uint2*)dst = make_uint2(lo, hi);                                   \
      }                                                                      \
    }                                                                        \
    _Pragma("unroll")                                                        \
    for (int ks = 0; ks < 2; ++ks) {                                         \
      const int pg = (ks * 4 + quad) ^ (m16 & 7);                            \
      const bf16x8 pb0 = *(const bf16x8*)(Pw0 + m16 * 32 + pg * 4);          \
      const bf16x8 pb1 = *(const bf16x8*)(Pw1 + m16 * 32 + pg * 4);          \
      _Pragma("unroll")                                                      \
      for (int dt = 0; dt < 4; ++dt) {                                       \
        const int d = dt * 16 + m16;                                         \
        const bf16x8 va = *(const bf16x8*)(&Vl[B][d * 64] + (((ks * 4 + quad) ^ (d & 7)) * 8)); \
        ot[0][dt] = __builtin_amdgcn_mfma_f32_16x16x32_bf16(va, pb0, ot[0][dt], 0, 0, 0); \
        ot[1][dt] = __builtin_amdgcn_mfma_f32_16x16x32_bf16(va, pb1, ot[1][dt], 0, 0, 0); \
      }                                                                      \
    }                                                                        \
  } while (0)

  PREFETCH(0, 0);
  __syncthreads();

  for (int kv0 = 0; kv0 < S; kv0 += 128) {
    PREFETCH(kv0 + 64, 1);
    STEP(0);
    __syncthreads();
    if (kv0 + 128 < S) PREFETCH(kv0 + 128, 0);
    STEP(1);
    __syncthreads();
  }
#undef PREFETCH
#undef STEP

  const int b = bh >> 4, h = bh & 15;
#pragma unroll
  for (int g = 0; g < 2; ++g) {
    float l = lr4[g][0] + lr4[g][1] + lr4[g][2] + lr4[g][3];
    l += __shfl_xor(l, 16, 64);
    l += __shfl_xor(l, 32, 64);
    const float inv = 1.0f / l;
    const int q = q0 + w * 32 + g * 16 + m16;
    u16* base = O + ((size_t)b * 2048 + q) * 1024 + h * 64;
#pragma unroll
    for (int dt = 0; dt < 4; ++dt) {
      const u32 lo = pk_bf16(ot[g][dt][0] * inv, ot[g][dt][1] * inv);
      const u32 hi = pk_bf16(ot[g][dt][2] * inv, ot[g][dt][3] * inv);
      *(uint2*)(base + dt * 16 + quad * 4) = make_uint2(lo, hi);
    }
  }
}

// ---------------- launch ----------------
extern "C" void kernel_launch(void* const* d_in, const int* in_sizes, int n_in,
                              void* d_out, int out_size, void* d_ws, size_t ws_size,
                              hipStream_t stream)
{
  const float* x     = (const float*)d_in[0];   // [2,2048,1024] f32
  const float* w_qkv = (const float*)d_in[1];   // [1024,3072]  f32
  const float* b_qkv = (const float*)d_in[2];   // [3072]       f32
  const float* w_out = (const float*)d_in[3];   // [1024,1024]  f32
  const float* b_out = (const float*)d_in[4];   // [1024]       f32
  float* out = (float*)d_out;                   // [2,2048,1024] f32

  u16* ws     = (u16*)d_ws;
  u16* xb     = ws;                          // [4096][1024] bf16
  u16* WtQKV  = xb + 4194304;                // [3072][1024] bf16
  u16* WtOut  = WtQKV + 3145728;             // [1024][1024] bf16
  u16* Qm     = WtOut + 1048576;             // [B,H,S,64]
  u16* Km     = Qm + 4194304;                // [B,H,S,64]
  u16* Vtm    = Km + 4194304;                // [B,H,64,S]  (written directly by gemm_qkv)
  u16* AO     = Vtm + 4194304;               // [B,S,E] bf16

  preprocess<<<3072, 256, 0, stream>>>(x, xb, w_qkv, WtQKV, w_out, WtOut);
  gemm_qkv<<<dim3(24, 32), 256, 0, stream>>>(xb, WtQKV, b_qkv, Qm, Km, Vtm);
  flash_attn<<<512, 256, 0, stream>>>(Qm, Km, Vtm, AO);
  gemm_out<<<dim3(8, 64), 256, 0, stream>>>(AO, WtOut, b_out, out);
}